// Round 8
// baseline (429.632 us; speedup 1.0000x reference)
//
#include <hip/hip_runtime.h>

#define S_LEN 2048
#define DIM 1024
#define NH 16
#define HD 64
#define KSPLIT 8

typedef __attribute__((ext_vector_type(8))) __bf16 bf16x8;
typedef __attribute__((ext_vector_type(4))) _Float16 f16x4;
typedef __attribute__((ext_vector_type(4))) float f32x4;
typedef __attribute__((ext_vector_type(8))) unsigned short us8;
typedef __attribute__((ext_vector_type(4))) unsigned short us4;

__device__ __forceinline__ unsigned short f2bf(float f) {
    union { float f; unsigned u; } v; v.f = f;
    unsigned r = v.u + 0x7FFFu + ((v.u >> 16) & 1u);   // RNE
    return (unsigned short)(r >> 16);
}
__device__ __forceinline__ float bf2f(unsigned short h) {
    union { unsigned u; float f; } v; v.u = ((unsigned)h) << 16;
    return v.f;
}
__device__ __forceinline__ f32x4 mfma16(bf16x8 a, bf16x8 b, f32x4 c) {
    return __builtin_amdgcn_mfma_f32_16x16x32_bf16(a, b, c, 0, 0, 0);
}
__device__ __forceinline__ f32x4 mfma16h(f16x4 a, f16x4 b, f32x4 c) {
    return __builtin_amdgcn_mfma_f32_16x16x16f16(a, b, c, 0, 0, 0);
}
__device__ __forceinline__ void gload_lds16(void* lds, const void* g) {
    __builtin_amdgcn_global_load_lds(
        (__attribute__((address_space(1))) void*)const_cast<void*>(g),
        (__attribute__((address_space(3))) void*)lds, 16, 0, 0);
}
// XOR swizzle for BK=32 tiles (4x16B chunks/row), conflict-free frag reads.
__device__ __forceinline__ int sw32(int row, int c) {   // -> ushort index
    const int p = row >> 1;
    return (p * 8 + ((((row & 1) << 2) | c) ^ (p & 7))) * 8;
}
// XOR swizzle for 64-elem rows (8x16B chunks/row)
__device__ __forceinline__ int sw64(int row, int c) {   // -> ushort index
    return (row * 8 + (c ^ (row & 7))) * 8;
}

// ---------------- fp32 -> bf16 convert: x (1024 blk), W_qkv (1536 blk) ----------------
__global__ __launch_bounds__(256) void convert2_kernel(
    const float* __restrict__ a, unsigned short* __restrict__ oa,
    const float* __restrict__ b, unsigned short* __restrict__ ob)
{
    const int bid = blockIdx.x;
    const float* in;
    unsigned short* out;
    int i;
    if (bid < 1024) { in = a; out = oa; i = (bid * 256 + threadIdx.x) * 8; }
    else            { in = b; out = ob; i = ((bid - 1024) * 256 + threadIdx.x) * 8; }
    const float4 p = *(const float4*)(in + i);
    const float4 q = *(const float4*)(in + i + 4);
    us8 o;
    o[0] = f2bf(p.x); o[1] = f2bf(p.y); o[2] = f2bf(p.z); o[3] = f2bf(p.w);
    o[4] = f2bf(q.x); o[5] = f2bf(q.y); o[6] = f2bf(q.z); o[7] = f2bf(q.w);
    *(us8*)(out + i) = o;
}

// ---------------- fused QKV GEMM 128x64 + RoPE + V-transpose ----------------
// grid (48,16) = 768 blocks (3/CU). Wave w: rows [32w,32w+32) x 64 cols.
// bx 0-15 -> q (roped, *0.125, bf16 into qkv), 16-31 -> k (roped), 32-47 -> v
// (f16 into Vt[h][d][s], transposed). Swizzled LDS: conflict-free frag reads.
__global__ __launch_bounds__(256) void gemm_qkv_fused_kernel(
    const unsigned short* __restrict__ A, const unsigned short* __restrict__ B,
    const float* __restrict__ bias, const float* __restrict__ sin_t,
    const float* __restrict__ cos_t, unsigned short* __restrict__ qkv,
    _Float16* __restrict__ Vt)
{
    __shared__ __align__(16) unsigned short As[128 * 32];
    __shared__ __align__(16) unsigned short Bs[64 * 32];

    const int tid  = threadIdx.x;
    const int w    = tid >> 6;
    const int lane = tid & 63;
    const int quad = lane >> 4;
    const int l15  = lane & 15;
    const int bm = blockIdx.y * 128, bn = blockIdx.x * 64;
    const int wm = w * 32;
    const int K = DIM;

    // staging decode: lane L -> (srow, skc) s.t. LDS dest base+L*16 lands at
    // the swizzled slot of (row = R0+srow, chunk = skc/8)
    const int pl   = lane >> 3;
    const int tt   = (lane & 7) ^ pl;
    const int srow = (pl << 1) | (tt >> 2);   // 0..15
    const int skc  = (tt & 3) << 3;           // 0,8,16,24

    f32x4 acc[2][4];
    const f32x4 zero4 = {0.f, 0.f, 0.f, 0.f};
    #pragma unroll
    for (int i = 0; i < 2; ++i)
        #pragma unroll
        for (int j = 0; j < 4; ++j) acc[i][j] = zero4;

    for (int k0 = 0; k0 < K; k0 += 32) {
        __syncthreads();
        #pragma unroll
        for (int t = 0; t < 2; ++t) {
            const int R0 = w * 32 + t * 16;
            gload_lds16(&As[R0 * 32], A + (size_t)(bm + R0 + srow) * K + k0 + skc);
        }
        gload_lds16(&Bs[(w * 16) * 32],
                    B + (size_t)(bn + w * 16 + srow) * K + k0 + skc);
        __syncthreads();

        bf16x8 a[2], b[4];
        #pragma unroll
        for (int i = 0; i < 2; ++i)
            a[i] = *(const bf16x8*)&As[sw32(wm + 16 * i + l15, quad)];
        #pragma unroll
        for (int j = 0; j < 4; ++j)
            b[j] = *(const bf16x8*)&Bs[sw32(16 * j + l15, quad)];
        #pragma unroll
        for (int i = 0; i < 2; ++i)
            #pragma unroll
            for (int j = 0; j < 4; ++j)
                acc[i][j] = mfma16(a[i], b[j], acc[i][j]);
    }

    const int sec = blockIdx.x >> 4;          // 0=q 1=k 2=v
    float bv[4];
    #pragma unroll
    for (int j = 0; j < 4; ++j) bv[j] = bias[bn + 16 * j + l15];

    if (sec < 2) {
        const float scale = (sec == 0) ? 0.125f : 1.0f;
        const int colb = bn + l15;            // + 16j
        #pragma unroll
        for (int i = 0; i < 2; ++i)
            #pragma unroll
            for (int r = 0; r < 4; ++r) {
                const int row = bm + wm + 16 * i + quad * 4 + r;   // s
                const float cv0 = cos_t[row * 64 + l15];
                const float sv0 = sin_t[row * 64 + l15];
                const float cv1 = cos_t[row * 64 + 16 + l15];
                const float sv1 = sin_t[row * 64 + 16 + l15];
                const float v0 = acc[i][0][r] + bv[0];
                const float v1 = acc[i][1][r] + bv[1];
                const float v2 = acc[i][2][r] + bv[2];
                const float v3 = acc[i][3][r] + bv[3];
                unsigned short* dst = qkv + (size_t)row * (3 * DIM) + colb;
                dst[0]  = f2bf((v0 * cv0 - v2 * sv0) * scale);
                dst[16] = f2bf((v1 * cv1 - v3 * sv1) * scale);
                dst[32] = f2bf((v2 * cv0 + v0 * sv0) * scale);
                dst[48] = f2bf((v3 * cv1 + v1 * sv1) * scale);
            }
    } else {
        const int vcolb = (blockIdx.x - 32) * 64;
        const int h = vcolb >> 6;
        #pragma unroll
        for (int j = 0; j < 4; ++j) {
            const int d = 16 * j + l15;
            #pragma unroll
            for (int i = 0; i < 2; ++i) {
                const int s0 = bm + wm + 16 * i + quad * 4;
                f16x4 o;
                #pragma unroll
                for (int r = 0; r < 4; ++r)
                    o[r] = (_Float16)(acc[i][j][r] + bv[j]);
                *(f16x4*)&Vt[(size_t)h * HD * S_LEN + (size_t)d * S_LEN + s0] = o;
            }
        }
    }
}

// ---------------- Flash attention: KSPLIT 8, 6 blocks/CU, prefetch ----------------
__global__ __launch_bounds__(256, 6) void attn_mfma_kernel(
    const unsigned short* __restrict__ qkv, const unsigned short* __restrict__ VtU,
    unsigned short* __restrict__ Opart, float* __restrict__ Lpart)
{
    __shared__ __align__(16) unsigned short Ks[64 * 64];
    __shared__ __align__(16) unsigned short Vts[64 * 64];

    const int h   = blockIdx.y;
    const int qb  = blockIdx.x * 128;
    const int ks  = blockIdx.z;
    const int kb0 = ks * (S_LEN / KSPLIT);
    const int tid  = threadIdx.x;
    const int w    = tid >> 6;
    const int lane = tid & 63;
    const int quad = lane >> 4;
    const int l15  = lane & 15;
    const int t7   = l15 & 7;
    const size_t hoff = (size_t)h * S_LEN * HD;

    bf16x8 aq[2][2];
    #pragma unroll
    for (int g = 0; g < 2; ++g)
        #pragma unroll
        for (int c = 0; c < 2; ++c)
            aq[g][c] = *(const bf16x8*)
                &qkv[(size_t)(qb + w * 32 + g * 16 + l15) * (3 * DIM) +
                     h * HD + 32 * c + quad * 8];

    const f32x4 zero4 = {0.f, 0.f, 0.f, 0.f};
    f32x4 o[2][4];
    #pragma unroll
    for (int g = 0; g < 2; ++g)
        #pragma unroll
        for (int dt = 0; dt < 4; ++dt) o[g][dt] = zero4;
    float lsum[2] = {0.f, 0.f};

    const int r0 = tid >> 3;
    const int c0 = tid & 7;

    us8 pk[2], pv[2];
    #pragma unroll
    for (int i = 0; i < 2; ++i) {
        const int row = r0 + 32 * i;
        pk[i] = *(const us8*)&qkv[(size_t)(kb0 + row) * (3 * DIM) +
                                  DIM + h * HD + c0 * 8];
        pv[i] = *(const us8*)&VtU[hoff + (size_t)row * S_LEN + kb0 + c0 * 8];
    }

    for (int kb = 0; kb < S_LEN / KSPLIT; kb += 64) {
        __syncthreads();
        #pragma unroll
        for (int i = 0; i < 2; ++i) {
            const int row = r0 + 32 * i;
            const int sw  = ((c0 ^ (row & 7)) << 3);
            *(us8*)&Ks[row * 64 + sw]  = pk[i];
            *(us8*)&Vts[row * 64 + sw] = pv[i];
        }
        __syncthreads();

        if (kb + 64 < S_LEN / KSPLIT) {
            #pragma unroll
            for (int i = 0; i < 2; ++i) {
                const int row = r0 + 32 * i;
                pk[i] = *(const us8*)&qkv[(size_t)(kb0 + kb + 64 + row) * (3 * DIM) +
                                          DIM + h * HD + c0 * 8];
                pv[i] = *(const us8*)&VtU[hoff + (size_t)row * S_LEN +
                                          kb0 + kb + 64 + c0 * 8];
            }
        }

        const _Float16* VtsH = (const _Float16*)Vts;
        #pragma unroll
        for (int g = 0; g < 2; ++g) {
            f32x4 s[4];
            #pragma unroll
            for (int kt = 0; kt < 4; ++kt) s[kt] = zero4;
            #pragma unroll
            for (int c = 0; c < 2; ++c)
                #pragma unroll
                for (int kt = 0; kt < 4; ++kt) {
                    const bf16x8 kf = *(const bf16x8*)
                        &Ks[(16 * kt + l15) * 64 + (((4 * c + quad) ^ t7) << 3)];
                    s[kt] = mfma16(kf, aq[g][c], s[kt]);
                }

            f16x4 pb[4];
            #pragma unroll
            for (int kt = 0; kt < 4; ++kt)
                #pragma unroll
                for (int r = 0; r < 4; ++r) {
                    const float p = __expf(s[kt][r]);
                    lsum[g] += p;
                    pb[kt][r] = (_Float16)p;
                }

            #pragma unroll
            for (int kt = 0; kt < 4; ++kt)
                #pragma unroll
                for (int dt = 0; dt < 4; ++dt) {
                    const f16x4 vf = *(const f16x4*)
                        &VtsH[(16 * dt + l15) * 64 +
                              (((2 * kt + (quad >> 1)) ^ t7) << 3) + (quad & 1) * 4];
                    o[g][dt] = mfma16h(pb[kt], vf, o[g][dt]);
                }
        }
    }

    #pragma unroll
    for (int g = 0; g < 2; ++g) {
        lsum[g] += __shfl_xor(lsum[g], 16);
        lsum[g] += __shfl_xor(lsum[g], 32);
        if (lane < 16)
            Lpart[((size_t)ks * NH + h) * S_LEN + qb + w * 32 + g * 16 + l15] = lsum[g];
    }

    #pragma unroll
    for (int g = 0; g < 2; ++g)
        #pragma unroll
        for (int dt = 0; dt < 4; ++dt)
            #pragma unroll
            for (int r = 0; r < 4; ++r) {
                const int row = qb + w * 32 + g * 16 + quad * 4 + r;
                Opart[(size_t)ks * S_LEN * DIM + (size_t)row * DIM +
                      h * HD + 16 * dt + l15] = f2bf(o[g][dt][r]);
            }
}

// ---------------- combine K-split partials -> bf16; also convert W_proj ----------------
__global__ __launch_bounds__(256) void combine_kernel(
    const unsigned short* __restrict__ Opart, const float* __restrict__ Lpart,
    unsigned short* __restrict__ outb,
    const float* __restrict__ Wp, unsigned short* __restrict__ wp_bf)
{
    const int bid = blockIdx.x;
    if (bid < 2048) {
        const int idx = (bid * 256 + threadIdx.x) * 4;
        const int q = idx >> 10, col = idx & 1023, h = col >> 6;
        float l = 0.f;
        float v0 = 0.f, v1 = 0.f, v2 = 0.f, v3 = 0.f;
        #pragma unroll
        for (int ks = 0; ks < KSPLIT; ++ks) {
            l += Lpart[((size_t)ks * NH + h) * S_LEN + q];
            const us4 a = *(const us4*)(Opart + (size_t)ks * S_LEN * DIM + idx);
            v0 += bf2f(a[0]); v1 += bf2f(a[1]); v2 += bf2f(a[2]); v3 += bf2f(a[3]);
        }
        const float rl = 1.0f / l;
        us4 ob;
        ob[0] = f2bf(v0 * rl); ob[1] = f2bf(v1 * rl);
        ob[2] = f2bf(v2 * rl); ob[3] = f2bf(v3 * rl);
        *(us4*)(outb + idx) = ob;
    } else {
        const int i = ((bid - 2048) * 256 + threadIdx.x) * 8;
        const float4 p = *(const float4*)(Wp + i);
        const float4 q = *(const float4*)(Wp + i + 4);
        us8 o;
        o[0] = f2bf(p.x); o[1] = f2bf(p.y); o[2] = f2bf(p.z); o[3] = f2bf(p.w);
        o[4] = f2bf(q.x); o[5] = f2bf(q.y); o[6] = f2bf(q.z); o[7] = f2bf(q.w);
        *(us8*)(wp_bf + i) = o;
    }
}

// ---------------- proj GEMM 64x64 tile, BK=64, swizzled: out = a @ Wp^T + b ----------------
__global__ __launch_bounds__(256) void gemm_proj_kernel(
    const unsigned short* __restrict__ A, const unsigned short* __restrict__ B,
    const float* __restrict__ bias, float* __restrict__ C,
    int M, int N, int K)
{
    __shared__ __align__(16) unsigned short As[64 * 64];
    __shared__ __align__(16) unsigned short Bs[64 * 64];

    const int tid  = threadIdx.x;
    const int w    = tid >> 6;
    const int lane = tid & 63;
    const int quad = lane >> 4;
    const int l15  = lane & 15;
    const int bm = blockIdx.y * 64, bn = blockIdx.x * 64;

    f32x4 acc[4];
    const f32x4 zero4 = {0.f, 0.f, 0.f, 0.f};
    #pragma unroll
    for (int j = 0; j < 4; ++j) acc[j] = zero4;

    for (int k0 = 0; k0 < K; k0 += 64) {
        __syncthreads();
        #pragma unroll
        for (int i2 = 0; i2 < 2; ++i2) {
            const int CI  = i2 * 256 + tid;
            const int row = CI >> 3;
            const int c   = (CI & 7) ^ (row & 7);
            const int base = (i2 * 256 + w * 64) * 8;   // wave-uniform
            gload_lds16(&As[base], A + (size_t)(bm + row) * K + k0 + c * 8);
            gload_lds16(&Bs[base], B + (size_t)(bn + row) * K + k0 + c * 8);
        }
        __syncthreads();

        #pragma unroll
        for (int c32 = 0; c32 < 2; ++c32) {
            const bf16x8 a = *(const bf16x8*)&As[sw64(w * 16 + l15, c32 * 4 + quad)];
            #pragma unroll
            for (int j = 0; j < 4; ++j) {
                const bf16x8 b = *(const bf16x8*)&Bs[sw64(16 * j + l15, c32 * 4 + quad)];
                acc[j] = mfma16(a, b, acc[j]);
            }
        }
    }

    #pragma unroll
    for (int j = 0; j < 4; ++j) {
        const int col = bn + 16 * j + l15;
        const float bv = bias[col];
        #pragma unroll
        for (int r = 0; r < 4; ++r) {
            const int row = bm + w * 16 + quad * 4 + r;
            C[(size_t)row * N + col] = acc[j][r] + bv;
        }
    }
}

extern "C" void kernel_launch(void* const* d_in, const int* in_sizes, int n_in,
                              void* d_out, int out_size, void* d_ws, size_t ws_size,
                              hipStream_t stream) {
    const float* x      = (const float*)d_in[0];
    const float* sin_t  = (const float*)d_in[1];
    const float* cos_t  = (const float*)d_in[2];
    const float* W_qkv  = (const float*)d_in[3];
    const float* b_qkv  = (const float*)d_in[4];
    const float* W_proj = (const float*)d_in[5];
    const float* b_proj = (const float*)d_in[6];
    float* out = (float*)d_out;

    char* ws = (char*)d_ws;
    unsigned short* qkv_bf = (unsigned short*)(ws);              // 12 MB  ph2-4 (q,k only)
    _Float16*       Vtbf   = (_Float16*)     (ws + 12582912);    //  4 MB  ph2-4
    unsigned short* Opart  = (unsigned short*)(ws + 16777216);   // 32 MB  ph4-5
    float*          Lpart  = (float*)        (ws + 50331648);    //  1 MB  ph4-5
    unsigned short* a_bf   = (unsigned short*)(ws + 51380224);   //  4 MB  ph5-6
    unsigned short* x_bf   = (unsigned short*)(ws + 55574528);   //  4 MB  ph1-2
    unsigned short* wp_bf  = (unsigned short*)(ws + 55574528);   //  2 MB  ph5-6 (over x_bf, dead)
    unsigned short* wq_bf  = (unsigned short*)(ws + 59768832);   //  6 MB  ph1-2

    const dim3 blk(256);

    convert2_kernel<<<dim3(2560), blk, 0, stream>>>(x, x_bf, W_qkv, wq_bf);

    gemm_qkv_fused_kernel<<<dim3(48, 16), blk, 0, stream>>>(
        x_bf, wq_bf, b_qkv, sin_t, cos_t, qkv_bf, Vtbf);

    attn_mfma_kernel<<<dim3(16, NH, KSPLIT), blk, 0, stream>>>(
        qkv_bf, (const unsigned short*)Vtbf, Opart, Lpart);

    combine_kernel<<<dim3(2560), blk, 0, stream>>>(
        Opart, Lpart, a_bf, W_proj, wp_bf);

    gemm_proj_kernel<<<dim3(16, 32), blk, 0, stream>>>(
        a_bf, wp_bf, b_proj, out, S_LEN, DIM, DIM);
}

// Round 9
// 157.668 us; speedup vs baseline: 2.7249x; 2.7249x over previous
//
#include <hip/hip_runtime.h>

#define S_LEN 2048
#define DIM 1024
#define NH 16
#define HD 64
#define KSPLIT 4

typedef __attribute__((ext_vector_type(8))) __bf16 bf16x8;
typedef __attribute__((ext_vector_type(4))) _Float16 f16x4;
typedef __attribute__((ext_vector_type(4))) float f32x4;
typedef __attribute__((ext_vector_type(8))) unsigned short us8;
typedef __attribute__((ext_vector_type(4))) unsigned short us4;

__device__ __forceinline__ unsigned short f2bf(float f) {
    union { float f; unsigned u; } v; v.f = f;
    unsigned r = v.u + 0x7FFFu + ((v.u >> 16) & 1u);   // RNE
    return (unsigned short)(r >> 16);
}
__device__ __forceinline__ float bf2f(unsigned short h) {
    union { unsigned u; float f; } v; v.u = ((unsigned)h) << 16;
    return v.f;
}
__device__ __forceinline__ f32x4 mfma16(bf16x8 a, bf16x8 b, f32x4 c) {
    return __builtin_amdgcn_mfma_f32_16x16x32_bf16(a, b, c, 0, 0, 0);
}
__device__ __forceinline__ f32x4 mfma16h(f16x4 a, f16x4 b, f32x4 c) {
    return __builtin_amdgcn_mfma_f32_16x16x16f16(a, b, c, 0, 0, 0);
}
__device__ __forceinline__ void gload_lds16(void* lds, const void* g) {
    __builtin_amdgcn_global_load_lds(
        (__attribute__((address_space(1))) void*)const_cast<void*>(g),
        (__attribute__((address_space(3))) void*)lds, 16, 0, 0);
}
// XOR swizzle for BK=32 tiles (4x16B chunks/row), conflict-free frag reads.
__device__ __forceinline__ int sw32(int row, int c) {   // -> ushort index
    const int p = row >> 1;
    return (p * 8 + ((((row & 1) << 2) | c) ^ (p & 7))) * 8;
}
// XOR swizzle for 64-elem rows (8x16B chunks/row)
__device__ __forceinline__ int sw64(int row, int c) {   // -> ushort index
    return (row * 8 + (c ^ (row & 7))) * 8;
}

// ---------------- fp32 -> bf16 convert: x (1024 blk), W_qkv (1536 blk) ----------------
__global__ __launch_bounds__(256) void convert2_kernel(
    const float* __restrict__ a, unsigned short* __restrict__ oa,
    const float* __restrict__ b, unsigned short* __restrict__ ob)
{
    const int bid = blockIdx.x;
    const float* in;
    unsigned short* out;
    int i;
    if (bid < 1024) { in = a; out = oa; i = (bid * 256 + threadIdx.x) * 8; }
    else            { in = b; out = ob; i = ((bid - 1024) * 256 + threadIdx.x) * 8; }
    const float4 p = *(const float4*)(in + i);
    const float4 q = *(const float4*)(in + i + 4);
    us8 o;
    o[0] = f2bf(p.x); o[1] = f2bf(p.y); o[2] = f2bf(p.z); o[3] = f2bf(p.w);
    o[4] = f2bf(q.x); o[5] = f2bf(q.y); o[6] = f2bf(q.z); o[7] = f2bf(q.w);
    *(us8*)(out + i) = o;
}

// ---------------- fused QKV GEMM 128x64 + RoPE + V-transpose ----------------
// grid (48,16) = 768 blocks (3/CU). Wave w: rows [32w,32w+32) x 64 cols.
// bx 0-15 -> q (roped, *0.125, bf16), 16-31 -> k (roped), 32-47 -> v (f16 Vt).
__global__ __launch_bounds__(256) void gemm_qkv_fused_kernel(
    const unsigned short* __restrict__ A, const unsigned short* __restrict__ B,
    const float* __restrict__ bias, const float* __restrict__ sin_t,
    const float* __restrict__ cos_t, unsigned short* __restrict__ qkv,
    _Float16* __restrict__ Vt)
{
    __shared__ __align__(16) unsigned short As[128 * 32];
    __shared__ __align__(16) unsigned short Bs[64 * 32];

    const int tid  = threadIdx.x;
    const int w    = tid >> 6;
    const int lane = tid & 63;
    const int quad = lane >> 4;
    const int l15  = lane & 15;
    const int bm = blockIdx.y * 128, bn = blockIdx.x * 64;
    const int wm = w * 32;
    const int K = DIM;

    const int pl   = lane >> 3;
    const int tt   = (lane & 7) ^ pl;
    const int srow = (pl << 1) | (tt >> 2);   // 0..15
    const int skc  = (tt & 3) << 3;           // 0,8,16,24

    f32x4 acc[2][4];
    const f32x4 zero4 = {0.f, 0.f, 0.f, 0.f};
    #pragma unroll
    for (int i = 0; i < 2; ++i)
        #pragma unroll
        for (int j = 0; j < 4; ++j) acc[i][j] = zero4;

    for (int k0 = 0; k0 < K; k0 += 32) {
        __syncthreads();
        #pragma unroll
        for (int t = 0; t < 2; ++t) {
            const int R0 = w * 32 + t * 16;
            gload_lds16(&As[R0 * 32], A + (size_t)(bm + R0 + srow) * K + k0 + skc);
        }
        gload_lds16(&Bs[(w * 16) * 32],
                    B + (size_t)(bn + w * 16 + srow) * K + k0 + skc);
        __syncthreads();

        bf16x8 a[2], b[4];
        #pragma unroll
        for (int i = 0; i < 2; ++i)
            a[i] = *(const bf16x8*)&As[sw32(wm + 16 * i + l15, quad)];
        #pragma unroll
        for (int j = 0; j < 4; ++j)
            b[j] = *(const bf16x8*)&Bs[sw32(16 * j + l15, quad)];
        #pragma unroll
        for (int i = 0; i < 2; ++i)
            #pragma unroll
            for (int j = 0; j < 4; ++j)
                acc[i][j] = mfma16(a[i], b[j], acc[i][j]);
    }

    const int sec = blockIdx.x >> 4;          // 0=q 1=k 2=v
    float bv[4];
    #pragma unroll
    for (int j = 0; j < 4; ++j) bv[j] = bias[bn + 16 * j + l15];

    if (sec < 2) {
        const float scale = (sec == 0) ? 0.125f : 1.0f;
        const int colb = bn + l15;            // + 16j
        #pragma unroll
        for (int i = 0; i < 2; ++i)
            #pragma unroll
            for (int r = 0; r < 4; ++r) {
                const int row = bm + wm + 16 * i + quad * 4 + r;   // s
                const float cv0 = cos_t[row * 64 + l15];
                const float sv0 = sin_t[row * 64 + l15];
                const float cv1 = cos_t[row * 64 + 16 + l15];
                const float sv1 = sin_t[row * 64 + 16 + l15];
                const float v0 = acc[i][0][r] + bv[0];
                const float v1 = acc[i][1][r] + bv[1];
                const float v2 = acc[i][2][r] + bv[2];
                const float v3 = acc[i][3][r] + bv[3];
                unsigned short* dst = qkv + (size_t)row * (3 * DIM) + colb;
                dst[0]  = f2bf((v0 * cv0 - v2 * sv0) * scale);
                dst[16] = f2bf((v1 * cv1 - v3 * sv1) * scale);
                dst[32] = f2bf((v2 * cv0 + v0 * sv0) * scale);
                dst[48] = f2bf((v3 * cv1 + v1 * sv1) * scale);
            }
    } else {
        const int vcolb = (blockIdx.x - 32) * 64;
        const int h = vcolb >> 6;
        #pragma unroll
        for (int j = 0; j < 4; ++j) {
            const int d = 16 * j + l15;
            #pragma unroll
            for (int i = 0; i < 2; ++i) {
                const int s0 = bm + wm + 16 * i + quad * 4;
                f16x4 o;
                #pragma unroll
                for (int r = 0; r < 4; ++r)
                    o[r] = (_Float16)(acc[i][j][r] + bv[j]);
                *(f16x4*)&Vt[(size_t)h * HD * S_LEN + (size_t)d * S_LEN + s0] = o;
            }
        }
    }
}

// ---------------- Flash attention: KSPLIT 4, (256,4) — no spills ----------------
__global__ __launch_bounds__(256, 4) void attn_mfma_kernel(
    const unsigned short* __restrict__ qkv, const unsigned short* __restrict__ VtU,
    unsigned short* __restrict__ Opart, float* __restrict__ Lpart)
{
    __shared__ __align__(16) unsigned short Ks[64 * 64];
    __shared__ __align__(16) unsigned short Vts[64 * 64];

    const int h   = blockIdx.y;
    const int qb  = blockIdx.x * 128;
    const int ks  = blockIdx.z;
    const int kb0 = ks * (S_LEN / KSPLIT);
    const int tid  = threadIdx.x;
    const int w    = tid >> 6;
    const int lane = tid & 63;
    const int quad = lane >> 4;
    const int l15  = lane & 15;
    const int t7   = l15 & 7;
    const size_t hoff = (size_t)h * S_LEN * HD;

    bf16x8 aq[2][2];
    #pragma unroll
    for (int g = 0; g < 2; ++g)
        #pragma unroll
        for (int c = 0; c < 2; ++c)
            aq[g][c] = *(const bf16x8*)
                &qkv[(size_t)(qb + w * 32 + g * 16 + l15) * (3 * DIM) +
                     h * HD + 32 * c + quad * 8];

    const f32x4 zero4 = {0.f, 0.f, 0.f, 0.f};
    f32x4 o[2][4];
    #pragma unroll
    for (int g = 0; g < 2; ++g)
        #pragma unroll
        for (int dt = 0; dt < 4; ++dt) o[g][dt] = zero4;
    float lsum[2] = {0.f, 0.f};

    const int r0 = tid >> 3;
    const int c0 = tid & 7;

    us8 pk[2], pv[2];
    #pragma unroll
    for (int i = 0; i < 2; ++i) {
        const int row = r0 + 32 * i;
        pk[i] = *(const us8*)&qkv[(size_t)(kb0 + row) * (3 * DIM) +
                                  DIM + h * HD + c0 * 8];
        pv[i] = *(const us8*)&VtU[hoff + (size_t)row * S_LEN + kb0 + c0 * 8];
    }

    for (int kb = 0; kb < S_LEN / KSPLIT; kb += 64) {
        __syncthreads();
        #pragma unroll
        for (int i = 0; i < 2; ++i) {
            const int row = r0 + 32 * i;
            const int sw  = ((c0 ^ (row & 7)) << 3);
            *(us8*)&Ks[row * 64 + sw]  = pk[i];
            *(us8*)&Vts[row * 64 + sw] = pv[i];
        }
        __syncthreads();

        if (kb + 64 < S_LEN / KSPLIT) {
            #pragma unroll
            for (int i = 0; i < 2; ++i) {
                const int row = r0 + 32 * i;
                pk[i] = *(const us8*)&qkv[(size_t)(kb0 + kb + 64 + row) * (3 * DIM) +
                                          DIM + h * HD + c0 * 8];
                pv[i] = *(const us8*)&VtU[hoff + (size_t)row * S_LEN +
                                          kb0 + kb + 64 + c0 * 8];
            }
        }

        const _Float16* VtsH = (const _Float16*)Vts;
        #pragma unroll
        for (int g = 0; g < 2; ++g) {
            f32x4 s[4];
            #pragma unroll
            for (int kt = 0; kt < 4; ++kt) s[kt] = zero4;
            #pragma unroll
            for (int c = 0; c < 2; ++c)
                #pragma unroll
                for (int kt = 0; kt < 4; ++kt) {
                    const bf16x8 kf = *(const bf16x8*)
                        &Ks[(16 * kt + l15) * 64 + (((4 * c + quad) ^ t7) << 3)];
                    s[kt] = mfma16(kf, aq[g][c], s[kt]);
                }

            f16x4 pb[4];
            #pragma unroll
            for (int kt = 0; kt < 4; ++kt)
                #pragma unroll
                for (int r = 0; r < 4; ++r) {
                    const float p = __expf(s[kt][r]);
                    lsum[g] += p;
                    pb[kt][r] = (_Float16)p;
                }

            #pragma unroll
            for (int kt = 0; kt < 4; ++kt)
                #pragma unroll
                for (int dt = 0; dt < 4; ++dt) {
                    const f16x4 vf = *(const f16x4*)
                        &VtsH[(16 * dt + l15) * 64 +
                              (((2 * kt + (quad >> 1)) ^ t7) << 3) + (quad & 1) * 4];
                    o[g][dt] = mfma16h(pb[kt], vf, o[g][dt]);
                }
        }
    }

    #pragma unroll
    for (int g = 0; g < 2; ++g) {
        lsum[g] += __shfl_xor(lsum[g], 16);
        lsum[g] += __shfl_xor(lsum[g], 32);
        if (lane < 16)
            Lpart[((size_t)ks * NH + h) * S_LEN + qb + w * 32 + g * 16 + l15] = lsum[g];
    }

    #pragma unroll
    for (int g = 0; g < 2; ++g)
        #pragma unroll
        for (int dt = 0; dt < 4; ++dt)
            #pragma unroll
            for (int r = 0; r < 4; ++r) {
                const int row = qb + w * 32 + g * 16 + quad * 4 + r;
                Opart[(size_t)ks * S_LEN * DIM + (size_t)row * DIM +
                      h * HD + 16 * dt + l15] = f2bf(o[g][dt][r]);
            }
}

// ---------------- combine K-split partials -> bf16; also convert W_proj ----------------
__global__ __launch_bounds__(256) void combine_kernel(
    const unsigned short* __restrict__ Opart, const float* __restrict__ Lpart,
    unsigned short* __restrict__ outb,
    const float* __restrict__ Wp, unsigned short* __restrict__ wp_bf)
{
    const int bid = blockIdx.x;
    if (bid < 2048) {
        const int idx = (bid * 256 + threadIdx.x) * 4;
        const int q = idx >> 10, col = idx & 1023, h = col >> 6;
        float l = 0.f;
        float v0 = 0.f, v1 = 0.f, v2 = 0.f, v3 = 0.f;
        #pragma unroll
        for (int ks = 0; ks < KSPLIT; ++ks) {
            l += Lpart[((size_t)ks * NH + h) * S_LEN + q];
            const us4 a = *(const us4*)(Opart + (size_t)ks * S_LEN * DIM + idx);
            v0 += bf2f(a[0]); v1 += bf2f(a[1]); v2 += bf2f(a[2]); v3 += bf2f(a[3]);
        }
        const float rl = 1.0f / l;
        us4 ob;
        ob[0] = f2bf(v0 * rl); ob[1] = f2bf(v1 * rl);
        ob[2] = f2bf(v2 * rl); ob[3] = f2bf(v3 * rl);
        *(us4*)(outb + idx) = ob;
    } else {
        const int i = ((bid - 2048) * 256 + threadIdx.x) * 8;
        const float4 p = *(const float4*)(Wp + i);
        const float4 q = *(const float4*)(Wp + i + 4);
        us8 o;
        o[0] = f2bf(p.x); o[1] = f2bf(p.y); o[2] = f2bf(p.z); o[3] = f2bf(p.w);
        o[4] = f2bf(q.x); o[5] = f2bf(q.y); o[6] = f2bf(q.z); o[7] = f2bf(q.w);
        *(us8*)(wp_bf + i) = o;
    }
}

// ---------------- proj GEMM 64x64 tile, BK=64, swizzled ----------------
__global__ __launch_bounds__(256) void gemm_proj_kernel(
    const unsigned short* __restrict__ A, const unsigned short* __restrict__ B,
    const float* __restrict__ bias, float* __restrict__ C,
    int M, int N, int K)
{
    __shared__ __align__(16) unsigned short As[64 * 64];
    __shared__ __align__(16) unsigned short Bs[64 * 64];

    const int tid  = threadIdx.x;
    const int w    = tid >> 6;
    const int lane = tid & 63;
    const int quad = lane >> 4;
    const int l15  = lane & 15;
    const int bm = blockIdx.y * 64, bn = blockIdx.x * 64;

    f32x4 acc[4];
    const f32x4 zero4 = {0.f, 0.f, 0.f, 0.f};
    #pragma unroll
    for (int j = 0; j < 4; ++j) acc[j] = zero4;

    for (int k0 = 0; k0 < K; k0 += 64) {
        __syncthreads();
        #pragma unroll
        for (int i2 = 0; i2 < 2; ++i2) {
            const int CI  = i2 * 256 + tid;
            const int row = CI >> 3;
            const int c   = (CI & 7) ^ (row & 7);
            const int base = (i2 * 256 + w * 64) * 8;   // wave-uniform
            gload_lds16(&As[base], A + (size_t)(bm + row) * K + k0 + c * 8);
            gload_lds16(&Bs[base], B + (size_t)(bn + row) * K + k0 + c * 8);
        }
        __syncthreads();

        #pragma unroll
        for (int c32 = 0; c32 < 2; ++c32) {
            const bf16x8 a = *(const bf16x8*)&As[sw64(w * 16 + l15, c32 * 4 + quad)];
            #pragma unroll
            for (int j = 0; j < 4; ++j) {
                const bf16x8 b = *(const bf16x8*)&Bs[sw64(16 * j + l15, c32 * 4 + quad)];
                acc[j] = mfma16(a, b, acc[j]);
            }
        }
    }

    #pragma unroll
    for (int j = 0; j < 4; ++j) {
        const int col = bn + 16 * j + l15;
        const float bv = bias[col];
        #pragma unroll
        for (int r = 0; r < 4; ++r) {
            const int row = bm + w * 16 + quad * 4 + r;
            C[(size_t)row * N + col] = acc[j][r] + bv;
        }
    }
}

extern "C" void kernel_launch(void* const* d_in, const int* in_sizes, int n_in,
                              void* d_out, int out_size, void* d_ws, size_t ws_size,
                              hipStream_t stream) {
    const float* x      = (const float*)d_in[0];
    const float* sin_t  = (const float*)d_in[1];
    const float* cos_t  = (const float*)d_in[2];
    const float* W_qkv  = (const float*)d_in[3];
    const float* b_qkv  = (const float*)d_in[4];
    const float* W_proj = (const float*)d_in[5];
    const float* b_proj = (const float*)d_in[6];
    float* out = (float*)d_out;

    char* ws = (char*)d_ws;
    unsigned short* qkv_bf = (unsigned short*)(ws);              // 12 MB  ph2-4 (q,k only)
    _Float16*       Vtbf   = (_Float16*)     (ws + 12582912);    //  4 MB  ph2-4
    unsigned short* Opart  = (unsigned short*)(ws + 16777216);   // 16 MB  ph4-5
    float*          Lpart  = (float*)        (ws + 33554432);    // .5 MB  ph4-5
    unsigned short* a_bf   = (unsigned short*)(ws + 34078720);   //  4 MB  ph5-6
    unsigned short* x_bf   = (unsigned short*)(ws + 38273024);   //  4 MB  ph1-2
    unsigned short* wp_bf  = (unsigned short*)(ws + 38273024);   //  2 MB  ph5-6 (over x_bf, dead)
    unsigned short* wq_bf  = (unsigned short*)(ws + 42467328);   //  6 MB  ph1-2

    const dim3 blk(256);

    convert2_kernel<<<dim3(2560), blk, 0, stream>>>(x, x_bf, W_qkv, wq_bf);

    gemm_qkv_fused_kernel<<<dim3(48, 16), blk, 0, stream>>>(
        x_bf, wq_bf, b_qkv, sin_t, cos_t, qkv_bf, Vtbf);

    attn_mfma_kernel<<<dim3(16, NH, KSPLIT), blk, 0, stream>>>(
        qkv_bf, (const unsigned short*)Vtbf, Opart, Lpart);

    combine_kernel<<<dim3(2560), blk, 0, stream>>>(
        Opart, Lpart, a_bf, W_proj, wp_bf);

    gemm_proj_kernel<<<dim3(16, 32), blk, 0, stream>>>(
        a_bf, wp_bf, b_proj, out, S_LEN, DIM, DIM);
}